// Round 2
// baseline (762.826 us; speedup 1.0000x reference)
//
#include <hip/hip_runtime.h>
#include <cstdint>

// LSTM cell: B=4096, N_IN=2048, N_OUT=2048.
// gates = [x|h_old](4096x4096) @ Wp^T + b ; Wp rows gate-interleaved: Wp[4j+q]=W_q[j].
// bf16 MFMA GEMM (128x128 tile, BK=32, global_load_lds w=16) with XOR-swizzled LDS
// K-chunks to kill the 8-way ds_read_b128 bank conflicts (R1: 4 extra cyc/read).
// Fused bias (acc init) + sigmoid/tanh + c/h epilogue via __shfl_xor gate gather.
// ws layout: t bf16 (32MB) @0, Wp bf16 (64MB) @32MB. Requires ws_size >= 96MB.

#define B_DIM 4096
#define NIN   2048
#define NOUT  2048
#define K_DIM 4096   // NIN + NOUT
#define NG    8192   // 4 * NOUT

#define BM 128
#define BN 128
#define BK 32

typedef __attribute__((ext_vector_type(8))) short bf16x8;  // 8 bf16 = 4 VGPRs
typedef __attribute__((ext_vector_type(4))) float f32x4;

__device__ inline unsigned short f2bf(float f) {
    uint32_t u = __float_as_uint(f);
    uint32_t r = (u + 0x7fffu + ((u >> 16) & 1u)) >> 16;   // round-to-nearest-even
    return (unsigned short)r;
}

__device__ inline float sel4(float a, float b, float c, float d, int s) {
    float x = (s & 1) ? b : a;
    float y = (s & 1) ? d : c;
    return (s & 2) ? y : x;
}

// ---- combined pack kernel ----
// blocks [0, TB)      : t = [x | h_old] row-major (B, K) bf16
// blocks [TB, TB+WB)  : Wp[4j+q][k] = W_q[j][k] bf16
#define TBLK ((B_DIM * K_DIM / 8) / 256)   // 8192
#define WBLK ((NG * K_DIM / 8) / 256)      // 16384
__global__ void pack_kernel(const float* __restrict__ x,
                            const float* __restrict__ h_old,
                            const float* __restrict__ Wf, const float* __restrict__ Wi,
                            const float* __restrict__ Wo, const float* __restrict__ Wg,
                            unsigned short* __restrict__ t,
                            unsigned short* __restrict__ Wp) {
    const float* src;
    unsigned short* dst;
    int idx;
    if (blockIdx.x < TBLK) {
        idx = blockIdx.x * 256 + threadIdx.x;
        int b = idx >> 9;                                 // K/8 = 512 chunks/row
        int k = (idx & 511) << 3;
        src = (k < NIN) ? (x + (size_t)b * NIN + k)
                        : (h_old + (size_t)b * NOUT + (k - NIN));
        dst = t;
    } else {
        idx = (blockIdx.x - TBLK) * 256 + threadIdx.x;
        int row = idx >> 9;
        int k = (idx & 511) << 3;
        int jf = row >> 2, q = row & 3;
        src = ((q == 0) ? Wf : (q == 1) ? Wi : (q == 2) ? Wo : Wg)
              + (size_t)jf * K_DIM + k;
        dst = Wp;
    }
    float4 lo = ((const float4*)src)[0];
    float4 hi = ((const float4*)src)[1];
    uint4 o;
    o.x = f2bf(lo.x) | ((uint32_t)f2bf(lo.y) << 16);
    o.y = f2bf(lo.z) | ((uint32_t)f2bf(lo.w) << 16);
    o.z = f2bf(hi.x) | ((uint32_t)f2bf(hi.y) << 16);
    o.w = f2bf(hi.z) | ((uint32_t)f2bf(hi.w) << 16);
    ((uint4*)dst)[idx] = o;
}

#define GL2LDS(g, l) \
    __builtin_amdgcn_global_load_lds((const __attribute__((address_space(1))) void*)(g), \
                                     (__attribute__((address_space(3))) void*)(l), 16, 0, 0)

// ---- fused GEMM + LSTM epilogue ----
__global__ __launch_bounds__(256)
void lstm_gemm_kernel(const unsigned short* __restrict__ T,   // (B, K) bf16
                      const unsigned short* __restrict__ Wp,  // (NG, K) bf16
                      const float* __restrict__ bf_, const float* __restrict__ bi_,
                      const float* __restrict__ bo_, const float* __restrict__ bg_,
                      const float* __restrict__ c_old,
                      float* __restrict__ c_out, float* __restrict__ h_out) {
    __shared__ __align__(16) unsigned short As[BM * BK];  // 8 KB
    __shared__ __align__(16) unsigned short Bs[BN * BK];  // 8 KB

    const int tid  = threadIdx.x;
    const int lane = tid & 63;
    const int w    = tid >> 6;
    const int m0   = blockIdx.y * BM;
    const int n0   = blockIdx.x * BN;
    const int wrow = (w >> 1) * 64;
    const int wcol = (w & 1) * 64;

    // staging: lane writes LDS at tid*16B (row=tid>>2, chunk pos=tid&3).
    // XOR swizzle: stored chunk position p holds logical chunk p ^ g(row),
    // g(row) = (row>>1)&3. So the global source chunk = (tid&3) ^ ((tid>>3)&3).
    const int arow = tid >> 2;                        // 0..63
    const int koff = (((tid & 3) ^ ((tid >> 3) & 3)) << 3);
    const unsigned short* Ag = T  + (size_t)(m0 + arow) * K_DIM + koff;
    const unsigned short* Bg = Wp + (size_t)(n0 + arow) * K_DIM + koff;

    // ---- bias folded into accumulator init ----
    // C/D map (16x16x32): col = lane&15, row = (lane>>4)*4 + r.
    // col n = n0+wcol+16j+(lane&15): gate q = n&3 = lane&3, feature = n>>2.
    const int q = lane & 3;
    const float* bsrc = (q == 0) ? bf_ : (q == 1) ? bi_ : (q == 2) ? bo_ : bg_;
    const int colbase = n0 + wcol + (lane & 15);
    f32x4 acc[4][4];
#pragma unroll
    for (int j = 0; j < 4; ++j) {
        float bj = bsrc[(colbase + 16 * j) >> 2];
        f32x4 bv = (f32x4){bj, bj, bj, bj};
#pragma unroll
        for (int i = 0; i < 4; ++i) acc[i][j] = bv;
    }

    const int rsel = lane & 15, ksel = lane >> 4;
    const int kswz = ksel ^ ((rsel >> 1) & 3);        // de-swizzled chunk position

    for (int kt = 0; kt < K_DIM; kt += BK) {
        GL2LDS(Ag + kt,                      As + tid * 8);
        GL2LDS(Ag + (size_t)64 * K_DIM + kt, As + 2048 + tid * 8);
        GL2LDS(Bg + kt,                      Bs + tid * 8);
        GL2LDS(Bg + (size_t)64 * K_DIM + kt, Bs + 2048 + tid * 8);
        __syncthreads();

        const bf16x8* Asv = (const bf16x8*)As;
        const bf16x8* Bsv = (const bf16x8*)Bs;
        bf16x8 af[4], bfr[4];
#pragma unroll
        for (int i = 0; i < 4; ++i)
            af[i] = Asv[(wrow + 16 * i + rsel) * 4 + kswz];
#pragma unroll
        for (int j = 0; j < 4; ++j)
            bfr[j] = Bsv[(wcol + 16 * j + rsel) * 4 + kswz];
#pragma unroll
        for (int i = 0; i < 4; ++i)
#pragma unroll
            for (int j = 0; j < 4; ++j)
                acc[i][j] = __builtin_amdgcn_mfma_f32_16x16x32_bf16(
                    af[i], bfr[j], acc[i][j], 0, 0, 0);
        __syncthreads();
    }

    // ---- epilogue ----
    const int rowbase = m0 + wrow + 4 * (lane >> 4);
#pragma unroll
    for (int i = 0; i < 4; ++i) {
#pragma unroll
        for (int j = 0; j < 4; ++j) {
            const int featbase = (n0 + wcol + 16 * j) >> 2;
#pragma unroll
            for (int r = 0; r < 4; ++r) {
                float z = acc[i][j][r];
                float v;
                if (q == 3) {                         // tanh for gate g
                    v = 1.f - 2.f / (__expf(2.f * z) + 1.f);
                } else {                              // sigmoid for f,i,o
                    v = 1.f / (1.f + __expf(-z));
                }
                float v1 = __shfl_xor(v, 1);
                float v2 = __shfl_xor(v, 2);
                float v3 = __shfl_xor(v, 3);
                float fg = sel4(v, v1, v2, v3, q);
                float ig = sel4(v, v1, v2, v3, q ^ 1);
                float og = sel4(v, v1, v2, v3, q ^ 2);
                float gg = sel4(v, v1, v2, v3, q ^ 3);
                if ((lane & 3) == r) {
                    const int row  = rowbase + 16 * i + r;
                    const int feat = featbase + ((lane & 15) >> 2);
                    const size_t off = (size_t)row * NOUT + feat;
                    float co = c_old[off];
                    float c  = fg * co + ig * gg;
                    float h  = og * (1.f - 2.f / (__expf(2.f * c) + 1.f));
                    c_out[off] = c;
                    h_out[off] = h;
                }
            }
        }
    }
}

extern "C" void kernel_launch(void* const* d_in, const int* in_sizes, int n_in,
                              void* d_out, int out_size, void* d_ws, size_t ws_size,
                              hipStream_t stream) {
    const float* c_old = (const float*)d_in[0];
    const float* h_old = (const float*)d_in[1];
    const float* x     = (const float*)d_in[2];
    const float* Wf    = (const float*)d_in[3];
    const float* bf_   = (const float*)d_in[4];
    const float* Wi    = (const float*)d_in[5];
    const float* bi_   = (const float*)d_in[6];
    const float* Wo    = (const float*)d_in[7];
    const float* bo_   = (const float*)d_in[8];
    const float* Wg    = (const float*)d_in[9];
    const float* bg_   = (const float*)d_in[10];

    unsigned short* t  = (unsigned short*)d_ws;                           // 32 MB
    unsigned short* Wp = (unsigned short*)d_ws + (size_t)B_DIM * K_DIM;   // 64 MB

    float* c_out = (float*)d_out;
    float* h_out = (float*)d_out + (size_t)B_DIM * NOUT;

    pack_kernel<<<TBLK + WBLK, 256, 0, stream>>>(x, h_old, Wf, Wi, Wo, Wg, t, Wp);

    dim3 grid(NG / BN, B_DIM / BM);   // 64 x 32
    lstm_gemm_kernel<<<grid, 256, 0, stream>>>(t, Wp, bf_, bi_, bo_, bg_,
                                               c_old, c_out, h_out);
}

// Round 3
// 626.417 us; speedup vs baseline: 1.2178x; 1.2178x over previous
//
#include <hip/hip_runtime.h>
#include <cstdint>

// LSTM cell: B=4096, N_IN=2048, N_OUT=2048.
// gates = [x|h_old](4096x4096) @ Wp^T + b ; Wp rows gate-interleaved: Wp[4j+q]=W_q[j].
// R3 = R1 structure (bias in epilogue, zero acc-init) + XOR LDS swizzle ONLY.
// ws layout: t bf16 (32MB) @0, Wp bf16 (64MB) @32MB. Requires ws_size >= 96MB.

#define B_DIM 4096
#define NIN   2048
#define NOUT  2048
#define K_DIM 4096   // NIN + NOUT
#define NG    8192   // 4 * NOUT

#define BM 128
#define BN 128
#define BK 32

typedef __attribute__((ext_vector_type(8))) short bf16x8;  // 8 bf16 = 4 VGPRs
typedef __attribute__((ext_vector_type(4))) float f32x4;

__device__ inline unsigned short f2bf(float f) {
    uint32_t u = __float_as_uint(f);
    uint32_t r = (u + 0x7fffu + ((u >> 16) & 1u)) >> 16;   // round-to-nearest-even
    return (unsigned short)r;
}

__device__ inline float sel4(float a, float b, float c, float d, int s) {
    float x = (s & 1) ? b : a;
    float y = (s & 1) ? d : c;
    return (s & 2) ? y : x;
}

// ---- combined pack kernel ----
#define TBLK ((B_DIM * K_DIM / 8) / 256)   // 8192
#define WBLK ((NG * K_DIM / 8) / 256)      // 16384
__global__ void pack_kernel(const float* __restrict__ x,
                            const float* __restrict__ h_old,
                            const float* __restrict__ Wf, const float* __restrict__ Wi,
                            const float* __restrict__ Wo, const float* __restrict__ Wg,
                            unsigned short* __restrict__ t,
                            unsigned short* __restrict__ Wp) {
    const float* src;
    unsigned short* dst;
    int idx;
    if (blockIdx.x < TBLK) {
        idx = blockIdx.x * 256 + threadIdx.x;
        int b = idx >> 9;                                 // K/8 = 512 chunks/row
        int k = (idx & 511) << 3;
        src = (k < NIN) ? (x + (size_t)b * NIN + k)
                        : (h_old + (size_t)b * NOUT + (k - NIN));
        dst = t;
    } else {
        idx = (blockIdx.x - TBLK) * 256 + threadIdx.x;
        int row = idx >> 9;
        int k = (idx & 511) << 3;
        int jf = row >> 2, q = row & 3;
        src = ((q == 0) ? Wf : (q == 1) ? Wi : (q == 2) ? Wo : Wg)
              + (size_t)jf * K_DIM + k;
        dst = Wp;
    }
    float4 lo = ((const float4*)src)[0];
    float4 hi = ((const float4*)src)[1];
    uint4 o;
    o.x = f2bf(lo.x) | ((uint32_t)f2bf(lo.y) << 16);
    o.y = f2bf(lo.z) | ((uint32_t)f2bf(lo.w) << 16);
    o.z = f2bf(hi.x) | ((uint32_t)f2bf(hi.y) << 16);
    o.w = f2bf(hi.z) | ((uint32_t)f2bf(hi.w) << 16);
    ((uint4*)dst)[idx] = o;
}

#define GL2LDS(g, l) \
    __builtin_amdgcn_global_load_lds((const __attribute__((address_space(1))) void*)(g), \
                                     (__attribute__((address_space(3))) void*)(l), 16, 0, 0)

// ---- fused GEMM + LSTM epilogue ----
__global__ __launch_bounds__(256)
void lstm_gemm_kernel(const unsigned short* __restrict__ T,   // (B, K) bf16
                      const unsigned short* __restrict__ Wp,  // (NG, K) bf16
                      const float* __restrict__ bf_, const float* __restrict__ bi_,
                      const float* __restrict__ bo_, const float* __restrict__ bg_,
                      const float* __restrict__ c_old,
                      float* __restrict__ c_out, float* __restrict__ h_out) {
    __shared__ __align__(16) unsigned short As[BM * BK];  // 8 KB
    __shared__ __align__(16) unsigned short Bs[BN * BK];  // 8 KB

    const int tid  = threadIdx.x;
    const int lane = tid & 63;
    const int w    = tid >> 6;
    const int m0   = blockIdx.y * BM;
    const int n0   = blockIdx.x * BN;
    const int wrow = (w >> 1) * 64;
    const int wcol = (w & 1) * 64;

    // staging: lane writes LDS at tid*16B (row=tid>>2, stored chunk pos=tid&3).
    // XOR swizzle: stored pos p holds logical chunk p ^ ((row>>1)&3), so the
    // global source chunk for this lane = (tid&3) ^ ((tid>>3)&3).
    const int arow = tid >> 2;                        // 0..63
    const int koff = (((tid & 3) ^ ((tid >> 3) & 3)) << 3);
    const unsigned short* Ag = T  + (size_t)(m0 + arow) * K_DIM + koff;
    const unsigned short* Bg = Wp + (size_t)(n0 + arow) * K_DIM + koff;

    f32x4 acc[4][4];
#pragma unroll
    for (int i = 0; i < 4; ++i)
#pragma unroll
        for (int j = 0; j < 4; ++j)
            acc[i][j] = (f32x4){0.f, 0.f, 0.f, 0.f};

    const int rsel = lane & 15, ksel = lane >> 4;
    const int kswz = ksel ^ ((rsel >> 1) & 3);        // de-swizzled chunk position

    for (int kt = 0; kt < K_DIM; kt += BK) {
        GL2LDS(Ag + kt,                      As + tid * 8);
        GL2LDS(Ag + (size_t)64 * K_DIM + kt, As + 2048 + tid * 8);
        GL2LDS(Bg + kt,                      Bs + tid * 8);
        GL2LDS(Bg + (size_t)64 * K_DIM + kt, Bs + 2048 + tid * 8);
        __syncthreads();

        const bf16x8* Asv = (const bf16x8*)As;
        const bf16x8* Bsv = (const bf16x8*)Bs;
        bf16x8 af[4], bfr[4];
#pragma unroll
        for (int i = 0; i < 4; ++i)
            af[i] = Asv[(wrow + 16 * i + rsel) * 4 + kswz];
#pragma unroll
        for (int j = 0; j < 4; ++j)
            bfr[j] = Bsv[(wcol + 16 * j + rsel) * 4 + kswz];
#pragma unroll
        for (int i = 0; i < 4; ++i)
#pragma unroll
            for (int j = 0; j < 4; ++j)
                acc[i][j] = __builtin_amdgcn_mfma_f32_16x16x32_bf16(
                    af[i], bfr[j], acc[i][j], 0, 0, 0);
        __syncthreads();
    }

    // ---- epilogue (identical to R1) ----
    // C/D map (16x16x32): col = lane&15, row = (lane>>4)*4 + r.
    // col n = n0+wcol+16j+(lane&15): gate q = n&3 = lane&3, feature = n>>2.
    const int q = lane & 3;
    const float* bsrc = (q == 0) ? bf_ : (q == 1) ? bi_ : (q == 2) ? bo_ : bg_;
    const int colbase = n0 + wcol + (lane & 15);
    float bias[4];
#pragma unroll
    for (int j = 0; j < 4; ++j)
        bias[j] = bsrc[(colbase + 16 * j) >> 2];

    const int rowbase = m0 + wrow + 4 * (lane >> 4);
#pragma unroll
    for (int i = 0; i < 4; ++i) {
#pragma unroll
        for (int j = 0; j < 4; ++j) {
            const int featbase = (n0 + wcol + 16 * j) >> 2;
#pragma unroll
            for (int r = 0; r < 4; ++r) {
                float z = acc[i][j][r] + bias[j];
                float v;
                if (q == 3) {                         // tanh for gate g
                    v = 1.f - 2.f / (__expf(2.f * z) + 1.f);
                } else {                              // sigmoid for f,i,o
                    v = 1.f / (1.f + __expf(-z));
                }
                float v1 = __shfl_xor(v, 1);
                float v2 = __shfl_xor(v, 2);
                float v3 = __shfl_xor(v, 3);
                float fg = sel4(v, v1, v2, v3, q);
                float ig = sel4(v, v1, v2, v3, q ^ 1);
                float og = sel4(v, v1, v2, v3, q ^ 2);
                float gg = sel4(v, v1, v2, v3, q ^ 3);
                if ((lane & 3) == r) {
                    const int row  = rowbase + 16 * i + r;
                    const int feat = featbase + ((lane & 15) >> 2);
                    const size_t off = (size_t)row * NOUT + feat;
                    float co = c_old[off];
                    float c  = fg * co + ig * gg;
                    float h  = og * (1.f - 2.f / (__expf(2.f * c) + 1.f));
                    c_out[off] = c;
                    h_out[off] = h;
                }
            }
        }
    }
}

extern "C" void kernel_launch(void* const* d_in, const int* in_sizes, int n_in,
                              void* d_out, int out_size, void* d_ws, size_t ws_size,
                              hipStream_t stream) {
    const float* c_old = (const float*)d_in[0];
    const float* h_old = (const float*)d_in[1];
    const float* x     = (const float*)d_in[2];
    const float* Wf    = (const float*)d_in[3];
    const float* bf_   = (const float*)d_in[4];
    const float* Wi    = (const float*)d_in[5];
    const float* bi_   = (const float*)d_in[6];
    const float* Wo    = (const float*)d_in[7];
    const float* bo_   = (const float*)d_in[8];
    const float* Wg    = (const float*)d_in[9];
    const float* bg_   = (const float*)d_in[10];

    unsigned short* t  = (unsigned short*)d_ws;                           // 32 MB
    unsigned short* Wp = (unsigned short*)d_ws + (size_t)B_DIM * K_DIM;   // 64 MB

    float* c_out = (float*)d_out;
    float* h_out = (float*)d_out + (size_t)B_DIM * NOUT;

    pack_kernel<<<TBLK + WBLK, 256, 0, stream>>>(x, h_old, Wf, Wi, Wo, Wg, t, Wp);

    dim3 grid(NG / BN, B_DIM / BM);   // 64 x 32
    lstm_gemm_kernel<<<grid, 256, 0, stream>>>(t, Wp, bf_, bi_, bo_, bg_,
                                               c_old, c_out, h_out);
}